// Round 2
// baseline (4751.170 us; speedup 1.0000x reference)
//
#include <hip/hip_runtime.h>
#include <hip/hip_bf16.h>
#include <math.h>

// ---------------- problem constants ----------------
#define BB 2
#define NN 2048
#define QD 1024
#define CTX_LEN 77
#define TCD 768
#define NUM_PROMPT 64
#define PD 1024
#define HEADS 8
#define DIM_HEAD 64
#define INNER 512            // HEADS*DIM_HEAD
#define JTOT (CTX_LEN + NUM_PROMPT + NN)   // 2189
#define SCALE 0.125f         // DIM_HEAD^-0.5

// ---------------- tiled GEMM: C[M,N] = A[M,K] @ W[K,N] (+bias) ----------------
// All f32. A row-major, W row-major.
// REMAP: map output row m -> (m>>11)*JTOT + 141 + (m&2047)  (x@w_img -> ctx rows)
// Requirements: K % 16 == 0, N % 64 == 0. M guarded.
#define BM 64
#define BN 64
#define BK 16

template <bool BIAS, bool REMAP>
__global__ __launch_bounds__(256) void gemm_kernel(
    const float* __restrict__ A, const float* __restrict__ W,
    float* __restrict__ C, const float* __restrict__ bias,
    int M, int K, int N) {
  __shared__ float As[BK][BM + 1];   // As[k][m]
  __shared__ float Ws[BK][BN + 1];   // Ws[k][n]
  const int t  = threadIdx.x;
  const int bm = blockIdx.y * BM;
  const int bn = blockIdx.x * BN;
  const int tx = t & 15, ty = t >> 4;

  float acc[4][4] = {};

  for (int k0 = 0; k0 < K; k0 += BK) {
#pragma unroll
    for (int i = 0; i < 4; ++i) {
      int l = t + i * 256;
      int m = l >> 4, kk = l & 15;
      int gm = bm + m;
      As[kk][m] = (gm < M) ? A[(size_t)gm * K + k0 + kk] : 0.f;
    }
#pragma unroll
    for (int i = 0; i < 4; ++i) {
      int l = t + i * 256;
      int kk = l >> 6, n = l & 63;
      Ws[kk][n] = W[(size_t)(k0 + kk) * N + bn + n];
    }
    __syncthreads();
#pragma unroll
    for (int kk = 0; kk < BK; ++kk) {
      float a[4], b[4];
#pragma unroll
      for (int i = 0; i < 4; ++i) a[i] = As[kk][ty * 4 + i];
#pragma unroll
      for (int j = 0; j < 4; ++j) b[j] = Ws[kk][tx * 4 + j];
#pragma unroll
      for (int i = 0; i < 4; ++i)
#pragma unroll
        for (int j = 0; j < 4; ++j) acc[i][j] += a[i] * b[j];
    }
    __syncthreads();
  }

#pragma unroll
  for (int i = 0; i < 4; ++i) {
    int gm = bm + ty * 4 + i;
    if (gm >= M) continue;
    size_t orow = REMAP ? (size_t)((gm >> 11) * JTOT + 141 + (gm & 2047)) : (size_t)gm;
#pragma unroll
    for (int j = 0; j < 4; ++j) {
      int gn = bn + tx * 4 + j;
      float v = acc[i][j];
      if (BIAS) v += bias[gn];
      C[orow * N + gn] = v;
    }
  }
}

// ---------------- ctx assembly: rows 0..76 = context, 77..140 = prompt_ctx ----------------
__global__ __launch_bounds__(256) void copy_ctx_kernel(
    const float* __restrict__ context,     // [B,77,768]
    const float* __restrict__ prompt_ctx,  // [64,768]
    float* __restrict__ ctx) {             // [B,JTOT,768]
  int idx = blockIdx.x * 256 + threadIdx.x;
  const int total = BB * 141 * TCD;
  if (idx >= total) return;
  int c = idx % TCD;
  int r = (idx / TCD) % 141;
  int b = idx / (141 * TCD);
  float v;
  if (r < CTX_LEN)
    v = context[((size_t)b * CTX_LEN + r) * TCD + c];
  else
    v = prompt_ctx[(size_t)(r - CTX_LEN) * TCD + c];
  ctx[((size_t)b * JTOT + r) * TCD + c] = v;
}

// ---------------- flash attention ----------------
// grid: B*H*(N/4) blocks of 256 threads (4 waves, 1 q-row per wave).
__global__ __launch_bounds__(256) void attn_kernel(
    const float* __restrict__ q, const float* __restrict__ k,
    const float* __restrict__ v, float* __restrict__ o) {
  __shared__ float kt[64][65];
  __shared__ float vt[64][65];
  __shared__ float qs[4][64];
  __shared__ float ss[4][64];

  const int t = threadIdx.x;
  const int w = t >> 6, lane = t & 63;
  const int blk = blockIdx.x;
  const int tile = blk & 511;        // N/4 = 512
  const int bh = blk >> 9;           // 0..15
  const int b = bh >> 3, h = bh & 7;
  const int row = tile * 4 + w;

  qs[w][lane] = q[((size_t)(b * NN + row)) * INNER + h * 64 + lane] * SCALE;

  float m = -INFINITY, lsum = 0.f, acc = 0.f;
  const size_t kvbase = (size_t)b * JTOT * INNER;
  const int ntiles = (JTOT + 63) / 64;   // 35

  for (int jt = 0; jt < ntiles; ++jt) {
    __syncthreads();   // covers qs on jt==0 and prev phase-B reads of vt
    const int j0 = jt * 64;
#pragma unroll
    for (int i = 0; i < 16; ++i) {
      int e = t + i * 256;
      int r = e >> 6, c = e & 63;
      int jg = j0 + r;
      float kk = 0.f, vv = 0.f;
      if (jg < JTOT) {
        size_t off = kvbase + (size_t)jg * INNER + h * 64 + c;
        kk = k[off];
        vv = v[off];
      }
      kt[r][c] = kk;
      vt[r][c] = vv;
    }
    __syncthreads();

    // phase A: lane = j within tile
    float s;
    if (j0 + lane < JTOT) {
      s = 0.f;
#pragma unroll
      for (int d = 0; d < 64; ++d) s += qs[w][d] * kt[lane][d];
    } else {
      s = -INFINITY;
    }
    ss[w][lane] = s;
    __syncthreads();

    // phase B: lane = output dim d; online softmax + PV
    float tmax = -INFINITY;
#pragma unroll
    for (int jj = 0; jj < 64; ++jj) tmax = fmaxf(tmax, ss[w][jj]);
    float newm = fmaxf(m, tmax);
    float alpha = __expf(m - newm);   // m=-inf on first tile -> 0
    lsum *= alpha;
    acc *= alpha;
#pragma unroll
    for (int jj = 0; jj < 64; ++jj) {
      float p = __expf(ss[w][jj] - newm);   // -inf pad -> 0
      lsum += p;
      acc += p * vt[jj][lane];
    }
    m = newm;
  }

  o[((size_t)(b * NN + row)) * INNER + h * 64 + lane] = acc / lsum;
}

// ---------------- launch ----------------
extern "C" void kernel_launch(void* const* d_in, const int* in_sizes, int n_in,
                              void* d_out, int out_size, void* d_ws, size_t ws_size,
                              hipStream_t stream) {
  const float* x        = (const float*)d_in[0];
  const float* context  = (const float*)d_in[1];
  const float* prompt   = (const float*)d_in[2];
  const float* w_prompt = (const float*)d_in[3];
  const float* w_img    = (const float*)d_in[4];
  const float* w_q      = (const float*)d_in[5];
  const float* w_k      = (const float*)d_in[6];
  const float* w_v      = (const float*)d_in[7];
  const float* w_out    = (const float*)d_in[8];
  const float* b_out    = (const float*)d_in[9];
  float* out = (float*)d_out;

  const int M = BB * NN;          // 4096
  const int MJ = BB * JTOT;       // 4378

  float* ws = (float*)d_ws;
  float* q_buf  = ws;                                  // 4096*512
  float* pc_buf = q_buf + (size_t)M * INNER;           // 64*768
  float* ctx    = pc_buf + (size_t)NUM_PROMPT * TCD;   // 4378*768
  float* k_buf  = ctx + (size_t)MJ * TCD;              // 4378*512
  float* v_buf  = k_buf + (size_t)MJ * INNER;          // 4378*512
  float* ao_buf = v_buf + (size_t)MJ * INNER;          // 4096*512

  // 1. prompt_ctx = prompt @ w_prompt   [64,1024]@[1024,768]
  gemm_kernel<false, false>
      <<<dim3(TCD / BN, 1), 256, 0, stream>>>(prompt, w_prompt, pc_buf, nullptr,
                                              NUM_PROMPT, PD, TCD);
  // 2. ctx rows 0..140 for both batches
  copy_ctx_kernel<<<(BB * 141 * TCD + 255) / 256, 256, 0, stream>>>(context, pc_buf, ctx);
  // 3. ctx img rows = x @ w_img   [4096,1024]@[1024,768], remapped rows
  gemm_kernel<false, true>
      <<<dim3(TCD / BN, M / BM), 256, 0, stream>>>(x, w_img, ctx, nullptr, M, QD, TCD);
  // 4. q = x @ w_q   [4096,1024]@[1024,512]
  gemm_kernel<false, false>
      <<<dim3(INNER / BN, M / BM), 256, 0, stream>>>(x, w_q, q_buf, nullptr, M, QD, INNER);
  // 5. k = ctx @ w_k   [4378,768]@[768,512]
  gemm_kernel<false, false>
      <<<dim3(INNER / BN, (MJ + BM - 1) / BM), 256, 0, stream>>>(ctx, w_k, k_buf, nullptr,
                                                                 MJ, TCD, INNER);
  // 6. v = ctx @ w_v
  gemm_kernel<false, false>
      <<<dim3(INNER / BN, (MJ + BM - 1) / BM), 256, 0, stream>>>(ctx, w_v, v_buf, nullptr,
                                                                 MJ, TCD, INNER);
  // 7. attention
  attn_kernel<<<BB * HEADS * (NN / 4), 256, 0, stream>>>(q_buf, k_buf, v_buf, ao_buf);
  // 8. out = attn_out @ w_out + b_out   [4096,512]@[512,1024]
  gemm_kernel<true, false>
      <<<dim3(QD / BN, M / BM), 256, 0, stream>>>(ao_buf, w_out, out, b_out, M, INNER, QD);
}

// Round 3
// 972.090 us; speedup vs baseline: 4.8876x; 4.8876x over previous
//
#include <hip/hip_runtime.h>
#include <hip/hip_bf16.h>
#include <math.h>

// ---------------- problem constants ----------------
#define BB 2
#define NN 2048
#define QD 1024
#define CTX_LEN 77
#define TCD 768
#define NUM_PROMPT 64
#define PD 1024
#define HEADS 8
#define DIM_HEAD 64
#define INNER 512            // HEADS*DIM_HEAD
#define JTOT (CTX_LEN + NUM_PROMPT + NN)   // 2189
#define SCALE 0.125f         // DIM_HEAD^-0.5

typedef __attribute__((ext_vector_type(8))) short bf16x8;
typedef __attribute__((ext_vector_type(4))) float f32x4;

// split f into hi/lo bf16 (truncation split), packed: low16=hi, high16=lo
__device__ __forceinline__ unsigned pack_split(float f) {
  unsigned u = __builtin_bit_cast(unsigned, f);
  unsigned hi = u & 0xffff0000u;
  float lo = f - __builtin_bit_cast(float, hi);
  unsigned ul = __builtin_bit_cast(unsigned, lo);
  // bytes: [u.b2, u.b3, ul.b2, ul.b3]
  return __builtin_amdgcn_perm(ul, u, 0x07060302u);
}

// 8 packed u32 -> hi frag (low halves) + lo frag (high halves)
__device__ __forceinline__ void unpack8(const unsigned* u, bf16x8& hf, bf16x8& lf) {
  union { unsigned w[4]; bf16x8 v; } H, L;
#pragma unroll
  for (int i = 0; i < 4; ++i) {
    H.w[i] = __builtin_amdgcn_perm(u[2 * i + 1], u[2 * i], 0x05040100u);
    L.w[i] = __builtin_amdgcn_perm(u[2 * i + 1], u[2 * i], 0x07060302u);
  }
  hf = H.v; lf = L.v;
}

// ---------------- tiled GEMM: C[M,N] = A[M,K] @ W[K,N] (+bias) ----------------
#define BM 64
#define BN 64
#define BK 16

template <bool BIAS, bool REMAP>
__global__ __launch_bounds__(256) void gemm_kernel(
    const float* __restrict__ A, const float* __restrict__ W,
    float* __restrict__ C, const float* __restrict__ bias,
    int M, int K, int N) {
  __shared__ float As[BK][BM + 1];   // As[k][m]
  __shared__ float Ws[BK][BN + 1];   // Ws[k][n]
  const int t  = threadIdx.x;
  const int bm = blockIdx.y * BM;
  const int bn = blockIdx.x * BN;
  const int tx = t & 15, ty = t >> 4;

  float acc[4][4] = {};

  for (int k0 = 0; k0 < K; k0 += BK) {
#pragma unroll
    for (int i = 0; i < 4; ++i) {
      int l = t + i * 256;
      int m = l >> 4, kk = l & 15;
      int gm = bm + m;
      As[kk][m] = (gm < M) ? A[(size_t)gm * K + k0 + kk] : 0.f;
    }
#pragma unroll
    for (int i = 0; i < 4; ++i) {
      int l = t + i * 256;
      int kk = l >> 6, n = l & 63;
      Ws[kk][n] = W[(size_t)(k0 + kk) * N + bn + n];
    }
    __syncthreads();
#pragma unroll
    for (int kk = 0; kk < BK; ++kk) {
      float a[4], b[4];
#pragma unroll
      for (int i = 0; i < 4; ++i) a[i] = As[kk][ty * 4 + i];
#pragma unroll
      for (int j = 0; j < 4; ++j) b[j] = Ws[kk][tx * 4 + j];
#pragma unroll
      for (int i = 0; i < 4; ++i)
#pragma unroll
        for (int j = 0; j < 4; ++j) acc[i][j] += a[i] * b[j];
    }
    __syncthreads();
  }

#pragma unroll
  for (int i = 0; i < 4; ++i) {
    int gm = bm + ty * 4 + i;
    if (gm >= M) continue;
    size_t orow = REMAP ? (size_t)((gm >> 11) * JTOT + 141 + (gm & 2047)) : (size_t)gm;
#pragma unroll
    for (int j = 0; j < 4; ++j) {
      int gn = bn + tx * 4 + j;
      float v = acc[i][j];
      if (BIAS) v += bias[gn];
      C[orow * N + gn] = v;
    }
  }
}

// ---------------- ctx assembly ----------------
__global__ __launch_bounds__(256) void copy_ctx_kernel(
    const float* __restrict__ context,     // [B,77,768]
    const float* __restrict__ prompt_ctx,  // [64,768]
    float* __restrict__ ctx) {             // [B,JTOT,768]
  int idx = blockIdx.x * 256 + threadIdx.x;
  const int total = BB * 141 * TCD;
  if (idx >= total) return;
  int c = idx % TCD;
  int r = (idx / TCD) % 141;
  int b = idx / (141 * TCD);
  float v;
  if (r < CTX_LEN)
    v = context[((size_t)b * CTX_LEN + r) * TCD + c];
  else
    v = prompt_ctx[(size_t)(r - CTX_LEN) * TCD + c];
  ctx[((size_t)b * JTOT + r) * TCD + c] = v;
}

// ---------------- MFMA flash attention (split-bf16) ----------------
// Block: 64 q-rows of one (b,h). 4 waves x 16 rows. J-tiles of 64.
// Layout facts (gfx950 16x16x32 bf16, HW-verified per guide):
//   C/D: row = quad*4+reg, col = lane&15
//   A:   m = lane&15, k = quad*8+j
//   B:   n = lane&15, k = quad*8+j
__global__ __launch_bounds__(256) void attn_mfma(
    const float* __restrict__ qg, const float* __restrict__ kg,
    const float* __restrict__ vg, float* __restrict__ o) {
  __shared__ __align__(16) unsigned Kp[64 * 68];  // [j][d] packed, stride 68
  __shared__ __align__(16) unsigned Vt[64 * 66];  // [d][j] packed, stride 66
  __shared__ __align__(16) unsigned Pp[64 * 68];  // [i][j] packed (also Q staging)

  const int t = threadIdx.x;
  const int w = t >> 6;
  const int lane = t & 63;
  const int m16 = lane & 15;
  const int quad = lane >> 4;

  const int blk = blockIdx.x;
  const int qt = blk & 31;             // 32 q-tiles (N/64)
  const int bh = blk >> 5;             // 0..15
  const int b = bh >> 3, h = bh & 7;
  const int qrow0 = qt * 64;

  const float* qb = qg + ((size_t)b * NN + qrow0) * INNER + h * 64;
  const float* kb = kg + (size_t)b * JTOT * INNER + h * 64;
  const float* vb = vg + (size_t)b * JTOT * INNER + h * 64;

  // ---- stage Q (pre-scaled) into Pp ----
#pragma unroll
  for (int i = 0; i < 4; ++i) {
    int idx4 = t + i * 256;
    int r = idx4 >> 4;           // q row in tile
    int dc = (idx4 & 15) * 4;    // d col base
    float4 f = *(const float4*)(qb + (size_t)r * INNER + dc);
    uint4 pk;
    pk.x = pack_split(f.x * SCALE);
    pk.y = pack_split(f.y * SCALE);
    pk.z = pack_split(f.z * SCALE);
    pk.w = pack_split(f.w * SCALE);
    *(uint4*)&Pp[r * 68 + dc] = pk;
  }
  __syncthreads();

  // ---- Q A-frags (kept in registers for whole loop) ----
  bf16x8 qh[2], ql[2];
#pragma unroll
  for (int ks = 0; ks < 2; ++ks) {
    const unsigned* p = &Pp[(w * 16 + m16) * 68 + ks * 32 + quad * 8];
    uint4 a = *(const uint4*)p, bq = *(const uint4*)(p + 4);
    unsigned u[8] = {a.x, a.y, a.z, a.w, bq.x, bq.y, bq.z, bq.w};
    unpack8(u, qh[ks], ql[ks]);
  }

  f32x4 O[4] = {{0.f,0.f,0.f,0.f},{0.f,0.f,0.f,0.f},{0.f,0.f,0.f,0.f},{0.f,0.f,0.f,0.f}};
  float mrow[4], lrow[4];
#pragma unroll
  for (int r = 0; r < 4; ++r) { mrow[r] = -INFINITY; lrow[r] = 0.f; }

  for (int j0 = 0; j0 < JTOT; j0 += 64) {
    __syncthreads();   // protect Kp/Vt from previous PV reads (and Pp Q-frag reads, iter 0)
    // ---- stage K (row-major packed) and V (transposed packed) ----
#pragma unroll
    for (int i = 0; i < 4; ++i) {
      int idx4 = t + i * 256;
      int jr = idx4 >> 4;
      int dc = (idx4 & 15) * 4;
      int jg = j0 + jr;
      float4 fk = {0.f, 0.f, 0.f, 0.f}, fv = {0.f, 0.f, 0.f, 0.f};
      if (jg < JTOT) {
        fk = *(const float4*)(kb + (size_t)jg * INNER + dc);
        fv = *(const float4*)(vb + (size_t)jg * INNER + dc);
      }
      uint4 pk;
      pk.x = pack_split(fk.x); pk.y = pack_split(fk.y);
      pk.z = pack_split(fk.z); pk.w = pack_split(fk.w);
      *(uint4*)&Kp[jr * 68 + dc] = pk;
      Vt[(dc + 0) * 66 + jr] = pack_split(fv.x);
      Vt[(dc + 1) * 66 + jr] = pack_split(fv.y);
      Vt[(dc + 2) * 66 + jr] = pack_split(fv.z);
      Vt[(dc + 3) * 66 + jr] = pack_split(fv.w);
    }
    __syncthreads();

    // ---- S = Q K^T (split: 3 MFMAs per k-step) ----
    f32x4 S[4];
#pragma unroll
    for (int jt = 0; jt < 4; ++jt) {
      f32x4 acc = {0.f, 0.f, 0.f, 0.f};
#pragma unroll
      for (int ks = 0; ks < 2; ++ks) {
        const unsigned* p = &Kp[(jt * 16 + m16) * 68 + ks * 32 + quad * 8];
        uint4 a = *(const uint4*)p, bq = *(const uint4*)(p + 4);
        unsigned u[8] = {a.x, a.y, a.z, a.w, bq.x, bq.y, bq.z, bq.w};
        bf16x8 kh, kl;
        unpack8(u, kh, kl);
        acc = __builtin_amdgcn_mfma_f32_16x16x32_bf16(qh[ks], kh, acc, 0, 0, 0);
        acc = __builtin_amdgcn_mfma_f32_16x16x32_bf16(qh[ks], kl, acc, 0, 0, 0);
        acc = __builtin_amdgcn_mfma_f32_16x16x32_bf16(ql[ks], kh, acc, 0, 0, 0);
      }
      S[jt] = acc;
    }

    // ---- mask invalid j columns ----
#pragma unroll
    for (int jt = 0; jt < 4; ++jt) {
      int jc = j0 + jt * 16 + m16;
      if (jc >= JTOT) {
#pragma unroll
        for (int r = 0; r < 4; ++r) S[jt][r] = -INFINITY;
      }
    }

    // ---- online softmax (row state redundant across the 16 lanes of a quad) ----
    float pj[4][4];
#pragma unroll
    for (int r = 0; r < 4; ++r) {
      float mx = fmaxf(fmaxf(S[0][r], S[1][r]), fmaxf(S[2][r], S[3][r]));
#pragma unroll
      for (int off = 1; off < 16; off <<= 1)
        mx = fmaxf(mx, __shfl_xor(mx, off, 64));
      float mnew = fmaxf(mrow[r], mx);
      float alpha = __expf(mrow[r] - mnew);   // first tile: exp(-inf)=0
      mrow[r] = mnew;
      float rs = 0.f;
#pragma unroll
      for (int jt = 0; jt < 4; ++jt) {
        float p = __expf(S[jt][r] - mnew);    // masked: exp(-inf)=0
        pj[jt][r] = p;
        rs += p;
      }
#pragma unroll
      for (int off = 1; off < 16; off <<= 1)
        rs += __shfl_xor(rs, off, 64);
      lrow[r] = lrow[r] * alpha + rs;
#pragma unroll
      for (int nt = 0; nt < 4; ++nt) O[nt][r] *= alpha;
    }

    // ---- write P (C-layout -> LDS, packed split) ----
#pragma unroll
    for (int jt = 0; jt < 4; ++jt)
#pragma unroll
      for (int r = 0; r < 4; ++r)
        Pp[(w * 16 + quad * 4 + r) * 68 + jt * 16 + m16] = pack_split(pj[jt][r]);
    __syncthreads();

    // ---- O += P V ----
    bf16x8 ph[2], pl[2];
#pragma unroll
    for (int ks = 0; ks < 2; ++ks) {
      const unsigned* p = &Pp[(w * 16 + m16) * 68 + ks * 32 + quad * 8];
      uint4 a = *(const uint4*)p, bq = *(const uint4*)(p + 4);
      unsigned u[8] = {a.x, a.y, a.z, a.w, bq.x, bq.y, bq.z, bq.w};
      unpack8(u, ph[ks], pl[ks]);
    }
#pragma unroll
    for (int nt = 0; nt < 4; ++nt) {
#pragma unroll
      for (int ks = 0; ks < 2; ++ks) {
        const unsigned* p = &Vt[(nt * 16 + m16) * 66 + ks * 32 + quad * 8];
        uint2 a = *(const uint2*)p,       b2 = *(const uint2*)(p + 2);
        uint2 c = *(const uint2*)(p + 4), d2 = *(const uint2*)(p + 6);
        unsigned u[8] = {a.x, a.y, b2.x, b2.y, c.x, c.y, d2.x, d2.y};
        bf16x8 vh, vl;
        unpack8(u, vh, vl);
        O[nt] = __builtin_amdgcn_mfma_f32_16x16x32_bf16(ph[ks], vh, O[nt], 0, 0, 0);
        O[nt] = __builtin_amdgcn_mfma_f32_16x16x32_bf16(ph[ks], vl, O[nt], 0, 0, 0);
        O[nt] = __builtin_amdgcn_mfma_f32_16x16x32_bf16(pl[ks], vh, O[nt], 0, 0, 0);
      }
    }
  }

  // ---- epilogue: normalize + store ----
  float inv[4];
#pragma unroll
  for (int r = 0; r < 4; ++r) inv[r] = 1.f / lrow[r];
  float* ob = o + ((size_t)b * NN + qrow0 + w * 16) * INNER + h * 64;
#pragma unroll
  for (int nt = 0; nt < 4; ++nt)
#pragma unroll
    for (int r = 0; r < 4; ++r)
      ob[(size_t)(quad * 4 + r) * INNER + nt * 16 + m16] = O[nt][r] * inv[r];
}

// ---------------- launch ----------------
extern "C" void kernel_launch(void* const* d_in, const int* in_sizes, int n_in,
                              void* d_out, int out_size, void* d_ws, size_t ws_size,
                              hipStream_t stream) {
  const float* x        = (const float*)d_in[0];
  const float* context  = (const float*)d_in[1];
  const float* prompt   = (const float*)d_in[2];
  const float* w_prompt = (const float*)d_in[3];
  const float* w_img    = (const float*)d_in[4];
  const float* w_q      = (const float*)d_in[5];
  const float* w_k      = (const float*)d_in[6];
  const float* w_v      = (const float*)d_in[7];
  const float* w_out    = (const float*)d_in[8];
  const float* b_out    = (const float*)d_in[9];
  float* out = (float*)d_out;

  const int M = BB * NN;          // 4096
  const int MJ = BB * JTOT;       // 4378

  float* ws = (float*)d_ws;
  float* q_buf  = ws;                                  // 4096*512
  float* pc_buf = q_buf + (size_t)M * INNER;           // 64*768
  float* ctx    = pc_buf + (size_t)NUM_PROMPT * TCD;   // 4378*768
  float* k_buf  = ctx + (size_t)MJ * TCD;              // 4378*512
  float* v_buf  = k_buf + (size_t)MJ * INNER;          // 4378*512
  float* ao_buf = v_buf + (size_t)MJ * INNER;          // 4096*512

  // 1. prompt_ctx = prompt @ w_prompt
  gemm_kernel<false, false>
      <<<dim3(TCD / BN, 1), 256, 0, stream>>>(prompt, w_prompt, pc_buf, nullptr,
                                              NUM_PROMPT, PD, TCD);
  // 2. ctx rows 0..140
  copy_ctx_kernel<<<(BB * 141 * TCD + 255) / 256, 256, 0, stream>>>(context, pc_buf, ctx);
  // 3. ctx img rows = x @ w_img (remapped)
  gemm_kernel<false, true>
      <<<dim3(TCD / BN, M / BM), 256, 0, stream>>>(x, w_img, ctx, nullptr, M, QD, TCD);
  // 4. q = x @ w_q
  gemm_kernel<false, false>
      <<<dim3(INNER / BN, M / BM), 256, 0, stream>>>(x, w_q, q_buf, nullptr, M, QD, INNER);
  // 5. k = ctx @ w_k
  gemm_kernel<false, false>
      <<<dim3(INNER / BN, (MJ + BM - 1) / BM), 256, 0, stream>>>(ctx, w_k, k_buf, nullptr,
                                                                 MJ, TCD, INNER);
  // 6. v = ctx @ w_v
  gemm_kernel<false, false>
      <<<dim3(INNER / BN, (MJ + BM - 1) / BM), 256, 0, stream>>>(ctx, w_v, v_buf, nullptr,
                                                                 MJ, TCD, INNER);
  // 7. attention (MFMA flash, split-bf16)
  attn_mfma<<<BB * HEADS * (NN / 64), 256, 0, stream>>>(q_buf, k_buf, v_buf, ao_buf);
  // 8. out = attn_out @ w_out + b_out
  gemm_kernel<true, false>
      <<<dim3(QD / BN, M / BM), 256, 0, stream>>>(ao_buf, w_out, out, b_out, M, INNER, QD);
}

// Round 4
// 473.554 us; speedup vs baseline: 10.0330x; 2.0528x over previous
//
#include <hip/hip_runtime.h>
#include <hip/hip_bf16.h>
#include <math.h>

// ---------------- problem constants ----------------
#define BB 2
#define NN 2048
#define QD 1024
#define CTX_LEN 77
#define TCD 768
#define NUM_PROMPT 64
#define PD 1024
#define HEADS 8
#define DIM_HEAD 64
#define INNER 512            // HEADS*DIM_HEAD
#define JTOT (CTX_LEN + NUM_PROMPT + NN)   // 2189
#define SCALE 0.125f         // DIM_HEAD^-0.5

typedef __attribute__((ext_vector_type(8))) short bf16x8;
typedef __attribute__((ext_vector_type(4))) float f32x4;

// split f into hi/lo bf16 (truncation split), packed u32: low16=hi, high16=lo
__device__ __forceinline__ unsigned pack_split(float f) {
  unsigned u = __builtin_bit_cast(unsigned, f);
  unsigned hi = u & 0xffff0000u;
  float lo = f - __builtin_bit_cast(float, hi);
  unsigned ul = __builtin_bit_cast(unsigned, lo);
  return __builtin_amdgcn_perm(ul, u, 0x07060302u);
}

// 8 packed u32 -> hi frag (low halves) + lo frag (high halves)
__device__ __forceinline__ void unpack8(const unsigned* u, bf16x8& hf, bf16x8& lf) {
  union { unsigned w[4]; bf16x8 v; } H, L;
#pragma unroll
  for (int i = 0; i < 4; ++i) {
    H.w[i] = __builtin_amdgcn_perm(u[2 * i + 1], u[2 * i], 0x05040100u);
    L.w[i] = __builtin_amdgcn_perm(u[2 * i + 1], u[2 * i], 0x07060302u);
  }
  hf = H.v; lf = L.v;
}

// ---------------- weight transpose+pack: src[K,N] f32 -> dst[N,K] packed u32 ----------------
__global__ __launch_bounds__(256) void transpose_pack(
    const float* __restrict__ src, unsigned* __restrict__ dst, int K, int N) {
  __shared__ unsigned T[32][33];
  const int t = threadIdx.x;
  const int k0 = blockIdx.y * 32, n0 = blockIdx.x * 32;
#pragma unroll
  for (int i = 0; i < 4; ++i) {
    int e = t + i * 256;
    int kr = e >> 5, nc = e & 31;
    T[kr][nc] = pack_split(src[(size_t)(k0 + kr) * N + n0 + nc]);
  }
  __syncthreads();
#pragma unroll
  for (int i = 0; i < 4; ++i) {
    int e = t + i * 256;
    int nr = e >> 5, kc = e & 31;
    dst[(size_t)(n0 + nr) * K + k0 + kc] = T[kc][nr];
  }
}

// ---------------- split-bf16 MFMA GEMM ----------------
// C[M,Ntot] = A[M,K](f32) @ Wt[Ntot,K](packed u32, transposed)
// 128x128 tile, BK=32 k-elems, 4 waves (2x2 quadrants of 64x64), 48 MFMA/wave/kstep.
// LDS row stride 36 u32: b128-aligned frags, bank-uniform.
// MODE 0: plain -> O1[M,Ntot] (gm guarded)
// MODE 1: n<TCD -> ctx (row remap (gm>>11)*JTOT+141+(gm&2047), ld TCD); else q (ld INNER)
// MODE 2: n<INNER -> k_buf else v_buf (ld INNER each, gm guarded)
// MODE 3: out (ld QD) + bias
#define LDSTR 36

template <int MODE>
__global__ __launch_bounds__(256) void gemm_mfma(
    const float* __restrict__ A, const unsigned* __restrict__ Wt,
    float* __restrict__ O1, float* __restrict__ O2, const float* __restrict__ bias,
    int M, int K, int Ntot) {
  __shared__ __align__(16) unsigned Au[128 * LDSTR];
  __shared__ __align__(16) unsigned Bu[128 * LDSTR];

  const int t = threadIdx.x;
  const int w = t >> 6, lane = t & 63;
  const int m16 = lane & 15, quad = lane >> 4;
  const int wm = w >> 1, wn = w & 1;
  const int bm = blockIdx.y * 128, bn = blockIdx.x * 128;

  const int srow = t >> 1, shalf = t & 1;     // staging: 2 threads/row, 16 u32 each
  const bool avalid = (bm + srow) < M;
  const float* ap = A + (size_t)(bm + srow) * K + shalf * 16;
  const unsigned* bp = Wt + (size_t)(bn + srow) * K + shalf * 16;
  const int sdst = srow * LDSTR + shalf * 16;

  f32x4 acc[4][4];
#pragma unroll
  for (int i = 0; i < 4; ++i)
#pragma unroll
    for (int j = 0; j < 4; ++j) acc[i][j] = (f32x4){0.f, 0.f, 0.f, 0.f};

  for (int k0 = 0; k0 < K; k0 += 32) {
    // ---- stage A (pack f32 -> split u32) ----
#pragma unroll
    for (int j = 0; j < 4; ++j) {
      float4 f = {0.f, 0.f, 0.f, 0.f};
      if (avalid) f = *(const float4*)(ap + k0 + j * 4);
      uint4 pk;
      pk.x = pack_split(f.x); pk.y = pack_split(f.y);
      pk.z = pack_split(f.z); pk.w = pack_split(f.w);
      *(uint4*)&Au[sdst + j * 4] = pk;
    }
    // ---- stage B (already packed) ----
#pragma unroll
    for (int j = 0; j < 4; ++j) {
      uint4 pk = *(const uint4*)(bp + k0 + j * 4);
      *(uint4*)&Bu[sdst + j * 4] = pk;
    }
    __syncthreads();

    // ---- fragments ----
    bf16x8 ah[4], al[4], bh[4], bl[4];
#pragma unroll
    for (int mt = 0; mt < 4; ++mt) {
      const unsigned* p = &Au[(wm * 64 + mt * 16 + m16) * LDSTR + quad * 8];
      uint4 x0 = *(const uint4*)p, x1 = *(const uint4*)(p + 4);
      unsigned u[8] = {x0.x, x0.y, x0.z, x0.w, x1.x, x1.y, x1.z, x1.w};
      unpack8(u, ah[mt], al[mt]);
    }
#pragma unroll
    for (int nt = 0; nt < 4; ++nt) {
      const unsigned* p = &Bu[(wn * 64 + nt * 16 + m16) * LDSTR + quad * 8];
      uint4 x0 = *(const uint4*)p, x1 = *(const uint4*)(p + 4);
      unsigned u[8] = {x0.x, x0.y, x0.z, x0.w, x1.x, x1.y, x1.z, x1.w};
      unpack8(u, bh[nt], bl[nt]);
    }
    // ---- 48 MFMAs: D = Ah*Bh + Ah*Bl + Al*Bh ----
#pragma unroll
    for (int mt = 0; mt < 4; ++mt)
#pragma unroll
      for (int nt = 0; nt < 4; ++nt) {
        acc[mt][nt] = __builtin_amdgcn_mfma_f32_16x16x32_bf16(ah[mt], bh[nt], acc[mt][nt], 0, 0, 0);
        acc[mt][nt] = __builtin_amdgcn_mfma_f32_16x16x32_bf16(ah[mt], bl[nt], acc[mt][nt], 0, 0, 0);
        acc[mt][nt] = __builtin_amdgcn_mfma_f32_16x16x32_bf16(al[mt], bh[nt], acc[mt][nt], 0, 0, 0);
      }
    __syncthreads();
  }

  // ---- epilogue ----
#pragma unroll
  for (int mt = 0; mt < 4; ++mt)
#pragma unroll
    for (int nt = 0; nt < 4; ++nt)
#pragma unroll
      for (int r = 0; r < 4; ++r) {
        int gm = bm + wm * 64 + mt * 16 + quad * 4 + r;
        int gn = bn + wn * 64 + nt * 16 + m16;
        float v = acc[mt][nt][r];
        if (MODE == 0) {
          if (gm < M) O1[(size_t)gm * Ntot + gn] = v;
        } else if (MODE == 1) {
          if (gn < TCD) {
            size_t row = (size_t)(gm >> 11) * JTOT + 141 + (gm & 2047);
            O1[row * TCD + gn] = v;
          } else {
            O2[(size_t)gm * INNER + (gn - TCD)] = v;
          }
        } else if (MODE == 2) {
          if (gm < M) {
            if (gn < INNER) O1[(size_t)gm * INNER + gn] = v;
            else            O2[(size_t)gm * INNER + (gn - INNER)] = v;
          }
        } else {  // MODE 3
          O1[(size_t)gm * QD + gn] = v + bias[gn];
        }
      }
}

// ---------------- ctx assembly ----------------
__global__ __launch_bounds__(256) void copy_ctx_kernel(
    const float* __restrict__ context,     // [B,77,768]
    const float* __restrict__ prompt_ctx,  // [64,768]
    float* __restrict__ ctx) {             // [B,JTOT,768]
  int idx = blockIdx.x * 256 + threadIdx.x;
  const int total = BB * 141 * TCD;
  if (idx >= total) return;
  int c = idx % TCD;
  int r = (idx / TCD) % 141;
  int b = idx / (141 * TCD);
  float v;
  if (r < CTX_LEN)
    v = context[((size_t)b * CTX_LEN + r) * TCD + c];
  else
    v = prompt_ctx[(size_t)(r - CTX_LEN) * TCD + c];
  ctx[((size_t)b * JTOT + r) * TCD + c] = v;
}

// ---------------- MFMA flash attention (split-bf16), unchanged from R3 ----------------
__global__ __launch_bounds__(256) void attn_mfma(
    const float* __restrict__ qg, const float* __restrict__ kg,
    const float* __restrict__ vg, float* __restrict__ o) {
  __shared__ __align__(16) unsigned Kp[64 * 68];  // [j][d] packed, stride 68
  __shared__ __align__(16) unsigned Vt[64 * 66];  // [d][j] packed, stride 66
  __shared__ __align__(16) unsigned Pp[64 * 68];  // [i][j] packed (also Q staging)

  const int t = threadIdx.x;
  const int w = t >> 6;
  const int lane = t & 63;
  const int m16 = lane & 15;
  const int quad = lane >> 4;

  const int blk = blockIdx.x;
  const int qt = blk & 31;
  const int bh = blk >> 5;
  const int b = bh >> 3, h = bh & 7;
  const int qrow0 = qt * 64;

  const float* qb = qg + ((size_t)b * NN + qrow0) * INNER + h * 64;
  const float* kb = kg + (size_t)b * JTOT * INNER + h * 64;
  const float* vb = vg + (size_t)b * JTOT * INNER + h * 64;

#pragma unroll
  for (int i = 0; i < 4; ++i) {
    int idx4 = t + i * 256;
    int r = idx4 >> 4;
    int dc = (idx4 & 15) * 4;
    float4 f = *(const float4*)(qb + (size_t)r * INNER + dc);
    uint4 pk;
    pk.x = pack_split(f.x * SCALE);
    pk.y = pack_split(f.y * SCALE);
    pk.z = pack_split(f.z * SCALE);
    pk.w = pack_split(f.w * SCALE);
    *(uint4*)&Pp[r * 68 + dc] = pk;
  }
  __syncthreads();

  bf16x8 qh[2], ql[2];
#pragma unroll
  for (int ks = 0; ks < 2; ++ks) {
    const unsigned* p = &Pp[(w * 16 + m16) * 68 + ks * 32 + quad * 8];
    uint4 a = *(const uint4*)p, bq = *(const uint4*)(p + 4);
    unsigned u[8] = {a.x, a.y, a.z, a.w, bq.x, bq.y, bq.z, bq.w};
    unpack8(u, qh[ks], ql[ks]);
  }

  f32x4 O[4] = {{0.f,0.f,0.f,0.f},{0.f,0.f,0.f,0.f},{0.f,0.f,0.f,0.f},{0.f,0.f,0.f,0.f}};
  float mrow[4], lrow[4];
#pragma unroll
  for (int r = 0; r < 4; ++r) { mrow[r] = -INFINITY; lrow[r] = 0.f; }

  for (int j0 = 0; j0 < JTOT; j0 += 64) {
    __syncthreads();
#pragma unroll
    for (int i = 0; i < 4; ++i) {
      int idx4 = t + i * 256;
      int jr = idx4 >> 4;
      int dc = (idx4 & 15) * 4;
      int jg = j0 + jr;
      float4 fk = {0.f, 0.f, 0.f, 0.f}, fv = {0.f, 0.f, 0.f, 0.f};
      if (jg < JTOT) {
        fk = *(const float4*)(kb + (size_t)jg * INNER + dc);
        fv = *(const float4*)(vb + (size_t)jg * INNER + dc);
      }
      uint4 pk;
      pk.x = pack_split(fk.x); pk.y = pack_split(fk.y);
      pk.z = pack_split(fk.z); pk.w = pack_split(fk.w);
      *(uint4*)&Kp[jr * 68 + dc] = pk;
      Vt[(dc + 0) * 66 + jr] = pack_split(fv.x);
      Vt[(dc + 1) * 66 + jr] = pack_split(fv.y);
      Vt[(dc + 2) * 66 + jr] = pack_split(fv.z);
      Vt[(dc + 3) * 66 + jr] = pack_split(fv.w);
    }
    __syncthreads();

    f32x4 S[4];
#pragma unroll
    for (int jt = 0; jt < 4; ++jt) {
      f32x4 acc = {0.f, 0.f, 0.f, 0.f};
#pragma unroll
      for (int ks = 0; ks < 2; ++ks) {
        const unsigned* p = &Kp[(jt * 16 + m16) * 68 + ks * 32 + quad * 8];
        uint4 a = *(const uint4*)p, bq = *(const uint4*)(p + 4);
        unsigned u[8] = {a.x, a.y, a.z, a.w, bq.x, bq.y, bq.z, bq.w};
        bf16x8 kh, kl;
        unpack8(u, kh, kl);
        acc = __builtin_amdgcn_mfma_f32_16x16x32_bf16(qh[ks], kh, acc, 0, 0, 0);
        acc = __builtin_amdgcn_mfma_f32_16x16x32_bf16(qh[ks], kl, acc, 0, 0, 0);
        acc = __builtin_amdgcn_mfma_f32_16x16x32_bf16(ql[ks], kh, acc, 0, 0, 0);
      }
      S[jt] = acc;
    }

#pragma unroll
    for (int jt = 0; jt < 4; ++jt) {
      int jc = j0 + jt * 16 + m16;
      if (jc >= JTOT) {
#pragma unroll
        for (int r = 0; r < 4; ++r) S[jt][r] = -INFINITY;
      }
    }

    float pj[4][4];
#pragma unroll
    for (int r = 0; r < 4; ++r) {
      float mx = fmaxf(fmaxf(S[0][r], S[1][r]), fmaxf(S[2][r], S[3][r]));
#pragma unroll
      for (int off = 1; off < 16; off <<= 1)
        mx = fmaxf(mx, __shfl_xor(mx, off, 64));
      float mnew = fmaxf(mrow[r], mx);
      float alpha = __expf(mrow[r] - mnew);
      mrow[r] = mnew;
      float rs = 0.f;
#pragma unroll
      for (int jt = 0; jt < 4; ++jt) {
        float p = __expf(S[jt][r] - mnew);
        pj[jt][r] = p;
        rs += p;
      }
#pragma unroll
      for (int off = 1; off < 16; off <<= 1)
        rs += __shfl_xor(rs, off, 64);
      lrow[r] = lrow[r] * alpha + rs;
#pragma unroll
      for (int nt = 0; nt < 4; ++nt) O[nt][r] *= alpha;
    }

#pragma unroll
    for (int jt = 0; jt < 4; ++jt)
#pragma unroll
      for (int r = 0; r < 4; ++r)
        Pp[(w * 16 + quad * 4 + r) * 68 + jt * 16 + m16] = pack_split(pj[jt][r]);
    __syncthreads();

    bf16x8 ph[2], pl[2];
#pragma unroll
    for (int ks = 0; ks < 2; ++ks) {
      const unsigned* p = &Pp[(w * 16 + m16) * 68 + ks * 32 + quad * 8];
      uint4 a = *(const uint4*)p, bq = *(const uint4*)(p + 4);
      unsigned u[8] = {a.x, a.y, a.z, a.w, bq.x, bq.y, bq.z, bq.w};
      unpack8(u, ph[ks], pl[ks]);
    }
#pragma unroll
    for (int nt = 0; nt < 4; ++nt) {
#pragma unroll
      for (int ks = 0; ks < 2; ++ks) {
        const unsigned* p = &Vt[(nt * 16 + m16) * 66 + ks * 32 + quad * 8];
        uint2 a = *(const uint2*)p,       b2 = *(const uint2*)(p + 2);
        uint2 c = *(const uint2*)(p + 4), d2 = *(const uint2*)(p + 6);
        unsigned u[8] = {a.x, a.y, b2.x, b2.y, c.x, c.y, d2.x, d2.y};
        bf16x8 vh, vl;
        unpack8(u, vh, vl);
        O[nt] = __builtin_amdgcn_mfma_f32_16x16x32_bf16(ph[ks], vh, O[nt], 0, 0, 0);
        O[nt] = __builtin_amdgcn_mfma_f32_16x16x32_bf16(ph[ks], vl, O[nt], 0, 0, 0);
        O[nt] = __builtin_amdgcn_mfma_f32_16x16x32_bf16(pl[ks], vh, O[nt], 0, 0, 0);
      }
    }
  }

  float inv[4];
#pragma unroll
  for (int r = 0; r < 4; ++r) inv[r] = 1.f / lrow[r];
  float* ob = o + ((size_t)b * NN + qrow0 + w * 16) * INNER + h * 64;
#pragma unroll
  for (int nt = 0; nt < 4; ++nt)
#pragma unroll
    for (int r = 0; r < 4; ++r)
      ob[(size_t)(quad * 4 + r) * INNER + nt * 16 + m16] = O[nt][r] * inv[r];
}

// ---------------- launch ----------------
extern "C" void kernel_launch(void* const* d_in, const int* in_sizes, int n_in,
                              void* d_out, int out_size, void* d_ws, size_t ws_size,
                              hipStream_t stream) {
  const float* x        = (const float*)d_in[0];
  const float* context  = (const float*)d_in[1];
  const float* prompt   = (const float*)d_in[2];
  const float* w_prompt = (const float*)d_in[3];
  const float* w_img    = (const float*)d_in[4];
  const float* w_q      = (const float*)d_in[5];
  const float* w_k      = (const float*)d_in[6];
  const float* w_v      = (const float*)d_in[7];
  const float* w_out    = (const float*)d_in[8];
  const float* b_out    = (const float*)d_in[9];
  float* out = (float*)d_out;

  const int M = BB * NN;          // 4096
  const int MJ = BB * JTOT;       // 4378

  float* ws = (float*)d_ws;
  float* q_buf  = ws;                                  // 4096*512
  float* pc_buf = q_buf + (size_t)M * INNER;           // 64*768
  float* ctx    = pc_buf + (size_t)NUM_PROMPT * TCD;   // 4378*768
  float* k_buf  = ctx + (size_t)MJ * TCD;              // 4378*512
  float* v_buf  = k_buf + (size_t)MJ * INNER;          // 4378*512
  float* ao_buf = v_buf + (size_t)MJ * INNER;          // 4096*512
  unsigned* WtP = (unsigned*)(ao_buf + (size_t)M * INNER);  // [768][1024]
  unsigned* WtA = WtP + (size_t)TCD * PD;                   // [1280][1024]
  unsigned* WtB = WtA + (size_t)(TCD + INNER) * QD;         // [1024][768]
  unsigned* WtO = WtB + (size_t)(2 * INNER) * TCD;          // [1024][512]

  // ---- pack+transpose weights ----
  transpose_pack<<<dim3(TCD / 32, PD / 32), 256, 0, stream>>>(w_prompt, WtP, PD, TCD);
  transpose_pack<<<dim3(TCD / 32, QD / 32), 256, 0, stream>>>(w_img, WtA, QD, TCD);
  transpose_pack<<<dim3(INNER / 32, QD / 32), 256, 0, stream>>>(w_q, WtA + (size_t)TCD * QD, QD, INNER);
  transpose_pack<<<dim3(INNER / 32, TCD / 32), 256, 0, stream>>>(w_k, WtB, TCD, INNER);
  transpose_pack<<<dim3(INNER / 32, TCD / 32), 256, 0, stream>>>(w_v, WtB + (size_t)INNER * TCD, TCD, INNER);
  transpose_pack<<<dim3(QD / 32, INNER / 32), 256, 0, stream>>>(w_out, WtO, INNER, QD);

  // ---- prompt_ctx = prompt @ w_prompt  [64,1024]@[1024,768] ----
  gemm_mfma<0><<<dim3(TCD / 128, 1), 256, 0, stream>>>(
      prompt, WtP, pc_buf, nullptr, nullptr, NUM_PROMPT, PD, TCD);
  // ---- ctx rows 0..140 ----
  copy_ctx_kernel<<<(BB * 141 * TCD + 255) / 256, 256, 0, stream>>>(context, pc_buf, ctx);
  // ---- fused: x @ [w_img | w_q]  -> ctx(img rows, remap) + q_buf ----
  gemm_mfma<1><<<dim3((TCD + INNER) / 128, M / 128), 256, 0, stream>>>(
      x, WtA, ctx, q_buf, nullptr, M, QD, TCD + INNER);
  // ---- fused: ctx @ [w_k | w_v] -> k_buf + v_buf ----
  gemm_mfma<2><<<dim3((2 * INNER) / 128, (MJ + 127) / 128), 256, 0, stream>>>(
      ctx, WtB, k_buf, v_buf, nullptr, MJ, TCD, 2 * INNER);
  // ---- attention ----
  attn_mfma<<<BB * HEADS * (NN / 64), 256, 0, stream>>>(q_buf, k_buf, v_buf, ao_buf);
  // ---- out = attn_out @ w_out + b_out ----
  gemm_mfma<3><<<dim3(QD / 128, M / 128), 256, 0, stream>>>(
      ao_buf, WtO, out, nullptr, b_out, M, INNER, QD);
}

// Round 5
// 464.091 us; speedup vs baseline: 10.2376x; 1.0204x over previous
//
#include <hip/hip_runtime.h>
#include <hip/hip_bf16.h>
#include <math.h>

// ---------------- problem constants ----------------
#define BB 2
#define NN 2048
#define QD 1024
#define CTX_LEN 77
#define TCD 768
#define NUM_PROMPT 64
#define PD 1024
#define HEADS 8
#define DIM_HEAD 64
#define INNER 512
#define JTOT (CTX_LEN + NUM_PROMPT + NN)   // 2189
#define SCALE 0.125f

typedef unsigned short u16;
typedef unsigned int u32;
typedef __attribute__((ext_vector_type(8))) short bf16x8;
typedef __attribute__((ext_vector_type(4))) float f32x4;

// ---- split helpers (numerics identical to R3/R4 pack_split) ----
__device__ __forceinline__ u32 pack_split(float f) {   // interleaved: low16=hi, high16=lo
  u32 u = __builtin_bit_cast(u32, f);
  u32 hi = u & 0xffff0000u;
  float lo = f - __builtin_bit_cast(float, hi);
  u32 ul = __builtin_bit_cast(u32, lo);
  return __builtin_amdgcn_perm(ul, u, 0x07060302u);
}
__device__ __forceinline__ void split2(float f, u16& h, u16& l) {
  u32 u = __builtin_bit_cast(u32, f);
  u32 hm = u & 0xffff0000u;
  float lo = f - __builtin_bit_cast(float, hm);
  h = (u16)(u >> 16);
  l = (u16)(__builtin_bit_cast(u32, lo) >> 16);
}
// 8 interleaved u32 -> hi/lo bf16x8 (for the P round-trip only)
__device__ __forceinline__ void unpack8(const u32* u, bf16x8& hf, bf16x8& lf) {
  union { u32 w[4]; bf16x8 v; } H, L;
#pragma unroll
  for (int i = 0; i < 4; ++i) {
    H.w[i] = __builtin_amdgcn_perm(u[2 * i + 1], u[2 * i], 0x05040100u);
    L.w[i] = __builtin_amdgcn_perm(u[2 * i + 1], u[2 * i], 0x07060302u);
  }
  hf = H.v; lf = L.v;
}
union U4B { uint4 q; bf16x8 v; };

// ---------------- weight transpose+pack: src[K,N] f32 -> hi/lo[N,K] bf16 planes ----------------
__global__ __launch_bounds__(256) void transpose_pack(
    const float* __restrict__ src, u16* __restrict__ dh, u16* __restrict__ dl,
    int K, int N) {
  __shared__ u32 T[32][33];
  const int t = threadIdx.x;
  const int k0 = blockIdx.y * 32, n0 = blockIdx.x * 32;
#pragma unroll
  for (int i = 0; i < 4; ++i) {
    int e = t + i * 256;
    int kr = e >> 5, nc = e & 31;
    T[kr][nc] = pack_split(src[(size_t)(k0 + kr) * N + n0 + nc]);
  }
  __syncthreads();
#pragma unroll
  for (int i = 0; i < 4; ++i) {
    int e = t + i * 256;
    int nr = e >> 5, kc = e & 31;
    u32 w = T[kc][nr];
    size_t idx = (size_t)(n0 + nr) * K + k0 + kc;
    dh[idx] = (u16)(w & 0xffff);
    dl[idx] = (u16)(w >> 16);
  }
}

// ---------------- split-bf16 MFMA GEMM (plane format) ----------------
// C[M,Ntot] = A[M,K] @ Wt[Ntot,K]^T ; A = f32 (AF32) or hi/lo planes.
// 128x128 tile, BK=32, 4 waves (2x2 of 64x64), 48 MFMA/wave/kstep.
// LDS: per plane, row = 16 u32 (32 bf16), stride 20 (16B-aligned, bank-uniform).
#define GST 20

template <int MODE, bool AF32>
__global__ __launch_bounds__(256) void gemm_mfma(
    const float* __restrict__ Af, const u16* __restrict__ Agh, const u16* __restrict__ Agl,
    const u16* __restrict__ Bgh, const u16* __restrict__ Bgl,
    u16* __restrict__ O1h, u16* __restrict__ O1l,
    u16* __restrict__ O2h, u16* __restrict__ O2l,
    float* __restrict__ Of, const float* __restrict__ bias,
    int M, int K, int Ntot) {
  __shared__ __align__(16) u32 Ah_s[128 * GST];
  __shared__ __align__(16) u32 Al_s[128 * GST];
  __shared__ __align__(16) u32 Bh_s[128 * GST];
  __shared__ __align__(16) u32 Bl_s[128 * GST];

  const int t = threadIdx.x;
  const int w = t >> 6, lane = t & 63;
  const int m16 = lane & 15, quad = lane >> 4;
  const int wm = w >> 1, wn = w & 1;
  const int bm = blockIdx.y * 128, bn = blockIdx.x * 128;

  const int srow = t >> 1, shalf = t & 1;
  const bool avalid = (bm + srow) < M;
  const int sdst = srow * GST + shalf * 8;
  const float* apf = Af ? (Af + (size_t)(bm + srow) * K + shalf * 16) : nullptr;
  const u16* aph = Agh ? (Agh + (size_t)(bm + srow) * K + shalf * 16) : nullptr;
  const u16* apl = Agl ? (Agl + (size_t)(bm + srow) * K + shalf * 16) : nullptr;
  const u16* bph = Bgh + (size_t)(bn + srow) * K + shalf * 16;
  const u16* bpl = Bgl + (size_t)(bn + srow) * K + shalf * 16;

  f32x4 acc[4][4];
#pragma unroll
  for (int i = 0; i < 4; ++i)
#pragma unroll
    for (int j = 0; j < 4; ++j) acc[i][j] = (f32x4){0.f, 0.f, 0.f, 0.f};

  const uint4 Z = {0u, 0u, 0u, 0u};

  for (int k0 = 0; k0 < K; k0 += 32) {
    if (AF32) {
      float4 fr[4];
#pragma unroll
      for (int j = 0; j < 4; ++j)
        fr[j] = avalid ? *(const float4*)(apf + k0 + j * 4) : (float4){0.f, 0.f, 0.f, 0.f};
      const float* f = (const float*)fr;
      u32 h[8], l[8];
#pragma unroll
      for (int e = 0; e < 8; ++e) {
        u32 u0 = __builtin_bit_cast(u32, f[2 * e]);
        u32 u1 = __builtin_bit_cast(u32, f[2 * e + 1]);
        h[e] = __builtin_amdgcn_perm(u1, u0, 0x07060302u);
        float lo0 = f[2 * e] - __builtin_bit_cast(float, u0 & 0xffff0000u);
        float lo1 = f[2 * e + 1] - __builtin_bit_cast(float, u1 & 0xffff0000u);
        l[e] = __builtin_amdgcn_perm(__builtin_bit_cast(u32, lo1),
                                     __builtin_bit_cast(u32, lo0), 0x07060302u);
      }
      *(uint4*)&Ah_s[sdst] = (uint4){h[0], h[1], h[2], h[3]};
      *(uint4*)&Ah_s[sdst + 4] = (uint4){h[4], h[5], h[6], h[7]};
      *(uint4*)&Al_s[sdst] = (uint4){l[0], l[1], l[2], l[3]};
      *(uint4*)&Al_s[sdst + 4] = (uint4){l[4], l[5], l[6], l[7]};
    } else {
      *(uint4*)&Ah_s[sdst]     = avalid ? *(const uint4*)(aph + k0) : Z;
      *(uint4*)&Ah_s[sdst + 4] = avalid ? *(const uint4*)(aph + k0 + 8) : Z;
      *(uint4*)&Al_s[sdst]     = avalid ? *(const uint4*)(apl + k0) : Z;
      *(uint4*)&Al_s[sdst + 4] = avalid ? *(const uint4*)(apl + k0 + 8) : Z;
    }
    *(uint4*)&Bh_s[sdst]     = *(const uint4*)(bph + k0);
    *(uint4*)&Bh_s[sdst + 4] = *(const uint4*)(bph + k0 + 8);
    *(uint4*)&Bl_s[sdst]     = *(const uint4*)(bpl + k0);
    *(uint4*)&Bl_s[sdst + 4] = *(const uint4*)(bpl + k0 + 8);
    __syncthreads();

    bf16x8 ah[4], al[4], bh[4], bl[4];
#pragma unroll
    for (int mt = 0; mt < 4; ++mt) {
      int off = (wm * 64 + mt * 16 + m16) * GST + quad * 4;
      ah[mt] = *(const bf16x8*)&Ah_s[off];
      al[mt] = *(const bf16x8*)&Al_s[off];
    }
#pragma unroll
    for (int nt = 0; nt < 4; ++nt) {
      int off = (wn * 64 + nt * 16 + m16) * GST + quad * 4;
      bh[nt] = *(const bf16x8*)&Bh_s[off];
      bl[nt] = *(const bf16x8*)&Bl_s[off];
    }
#pragma unroll
    for (int mt = 0; mt < 4; ++mt)
#pragma unroll
      for (int nt = 0; nt < 4; ++nt) {
        acc[mt][nt] = __builtin_amdgcn_mfma_f32_16x16x32_bf16(ah[mt], bh[nt], acc[mt][nt], 0, 0, 0);
        acc[mt][nt] = __builtin_amdgcn_mfma_f32_16x16x32_bf16(ah[mt], bl[nt], acc[mt][nt], 0, 0, 0);
        acc[mt][nt] = __builtin_amdgcn_mfma_f32_16x16x32_bf16(al[mt], bh[nt], acc[mt][nt], 0, 0, 0);
      }
    __syncthreads();
  }

  // ---- epilogue ----
#pragma unroll
  for (int mt = 0; mt < 4; ++mt)
#pragma unroll
    for (int nt = 0; nt < 4; ++nt)
#pragma unroll
      for (int r = 0; r < 4; ++r) {
        int gm = bm + wm * 64 + mt * 16 + quad * 4 + r;
        int gn = bn + wn * 64 + nt * 16 + m16;
        float v = acc[mt][nt][r];
        u16 hh, ll;
        if (MODE == 0) {
          if (gm < M) {
            split2(v, hh, ll);
            size_t idx = (size_t)gm * Ntot + gn;
            O1h[idx] = hh; O1l[idx] = ll;
          }
        } else if (MODE == 1) {
          if (gn < TCD) {
            split2(v, hh, ll);
            size_t row = (size_t)(gm >> 11) * JTOT + 141 + (gm & 2047);
            O1h[row * TCD + gn] = hh; O1l[row * TCD + gn] = ll;
          } else {
            split2(v * SCALE, hh, ll);
            size_t idx = (size_t)gm * INNER + (gn - TCD);
            O2h[idx] = hh; O2l[idx] = ll;
          }
        } else if (MODE == 2) {
          if (gm < M) {
            split2(v, hh, ll);
            if (gn < INNER) {
              size_t idx = (size_t)gm * INNER + gn;
              O1h[idx] = hh; O1l[idx] = ll;
            } else {
              size_t idx = (size_t)gm * INNER + (gn - INNER);
              O2h[idx] = hh; O2l[idx] = ll;
            }
          }
        } else {
          Of[(size_t)gm * QD + gn] = v + bias[gn];
        }
      }
}

// ---------------- ctx assembly (planes) ----------------
__global__ __launch_bounds__(256) void copy_ctx_kernel(
    const float* __restrict__ context, const u16* __restrict__ pch,
    const u16* __restrict__ pcl, u16* __restrict__ ch, u16* __restrict__ cl) {
  int idx = blockIdx.x * 256 + threadIdx.x;
  const int total = BB * 141 * TCD;
  if (idx >= total) return;
  int c = idx % TCD;
  int r = (idx / TCD) % 141;
  int b = idx / (141 * TCD);
  size_t dst = ((size_t)b * JTOT + r) * TCD + c;
  if (r < CTX_LEN) {
    u16 hh, ll;
    split2(context[((size_t)b * CTX_LEN + r) * TCD + c], hh, ll);
    ch[dst] = hh; cl[dst] = ll;
  } else {
    size_t s = (size_t)(r - CTX_LEN) * TCD + c;
    ch[dst] = pch[s]; cl[dst] = pcl[s];
  }
}

// ---------------- MFMA flash attention (plane format) ----------------
// Block: 64 q-rows of one (b,h). 4 waves x 16 rows. J-tiles of 64.
// LDS (u32): Kh/Kl [64][36], Wh/Wl [64][36] (Q staging, then Vt[d][j-pair]),
// Pp [64][68] interleaved.
#define AST 36

__global__ __launch_bounds__(256) void attn_mfma(
    const u16* __restrict__ qgh, const u16* __restrict__ qgl,
    const u16* __restrict__ kgh, const u16* __restrict__ kgl,
    const u16* __restrict__ vgh, const u16* __restrict__ vgl,
    u16* __restrict__ aoh, u16* __restrict__ aol) {
  __shared__ __align__(16) u32 lds[4 * 64 * AST + 64 * 68];
  u32* Kh = lds;
  u32* Kl = lds + 64 * AST;
  u32* Wh = lds + 2 * 64 * AST;
  u32* Wl = lds + 3 * 64 * AST;
  u32* Pp = lds + 4 * 64 * AST;

  const int t = threadIdx.x;
  const int w = t >> 6, lane = t & 63;
  const int m16 = lane & 15, quad = lane >> 4;
  const int blk = blockIdx.x;
  const int qt = blk & 31;
  const int bh = blk >> 5;
  const int b = bh >> 3, h = bh & 7;
  const int qrow0 = qt * 64;

  // ---- stage Q (pre-scaled planes) ----
  {
    int r = t >> 2, ch = t & 3;
    size_t off = ((size_t)(b * NN + qrow0 + r)) * INNER + h * 64 + ch * 16;
    int d = r * AST + ch * 8;
    *(uint4*)&Wh[d]     = *(const uint4*)(qgh + off);
    *(uint4*)&Wh[d + 4] = *(const uint4*)(qgh + off + 8);
    *(uint4*)&Wl[d]     = *(const uint4*)(qgl + off);
    *(uint4*)&Wl[d + 4] = *(const uint4*)(qgl + off + 8);
  }
  __syncthreads();

  bf16x8 qfh[2], qfl[2];
#pragma unroll
  for (int ks = 0; ks < 2; ++ks) {
    int off = (w * 16 + m16) * AST + ks * 16 + quad * 4;
    qfh[ks] = *(const bf16x8*)&Wh[off];
    qfl[ks] = *(const bf16x8*)&Wl[off];
  }

  f32x4 O[4] = {{0.f,0.f,0.f,0.f},{0.f,0.f,0.f,0.f},{0.f,0.f,0.f,0.f},{0.f,0.f,0.f,0.f}};
  float mrow[4], lrow[4];
#pragma unroll
  for (int r = 0; r < 4; ++r) { mrow[r] = -INFINITY; lrow[r] = 0.f; }

  const uint4 Z = {0u, 0u, 0u, 0u};
  const size_t kvbase = (size_t)b * JTOT * INNER + h * 64;

  for (int j0 = 0; j0 < JTOT; j0 += 64) {
    __syncthreads();   // prev-tile frag reads done (and Q frags on iter 0)
    // ---- stage K (plane copy) ----
    {
      int r = t >> 2, ch = t & 3;
      int jg = j0 + r;
      bool ok = jg < JTOT;
      size_t off = kvbase + (size_t)jg * INNER + ch * 16;
      int d = r * AST + ch * 8;
      *(uint4*)&Kh[d]     = ok ? *(const uint4*)(kgh + off) : Z;
      *(uint4*)&Kh[d + 4] = ok ? *(const uint4*)(kgh + off + 8) : Z;
      *(uint4*)&Kl[d]     = ok ? *(const uint4*)(kgl + off) : Z;
      *(uint4*)&Kl[d + 4] = ok ? *(const uint4*)(kgl + off + 8) : Z;
    }
    // ---- stage V (pair-transpose into Vt[d][j-pair]) ----
    {
      int p = t & 31, dch = t >> 5;          // p: j-pair, dch: 8-d chunk
      int ja = j0 + 2 * p, jb = ja + 1;
      size_t offa = kvbase + (size_t)ja * INNER + dch * 8;
      uint4 vah = (ja < JTOT) ? *(const uint4*)(vgh + offa) : Z;
      uint4 vbh = (jb < JTOT) ? *(const uint4*)(vgh + offa + INNER) : Z;
      uint4 val = (ja < JTOT) ? *(const uint4*)(vgl + offa) : Z;
      uint4 vbl = (jb < JTOT) ? *(const uint4*)(vgl + offa + INNER) : Z;
      const u32* a0 = (const u32*)&vah; const u32* b0 = (const u32*)&vbh;
      const u32* a1 = (const u32*)&val; const u32* b1 = (const u32*)&vbl;
#pragma unroll
      for (int i = 0; i < 4; ++i) {
        Wh[(dch * 8 + 2 * i) * AST + p]     = __builtin_amdgcn_perm(b0[i], a0[i], 0x05040100u);
        Wh[(dch * 8 + 2 * i + 1) * AST + p] = __builtin_amdgcn_perm(b0[i], a0[i], 0x07060302u);
        Wl[(dch * 8 + 2 * i) * AST + p]     = __builtin_amdgcn_perm(b1[i], a1[i], 0x05040100u);
        Wl[(dch * 8 + 2 * i + 1) * AST + p] = __builtin_amdgcn_perm(b1[i], a1[i], 0x07060302u);
      }
    }
    __syncthreads();

    // ---- S = Q K^T ----
    f32x4 S[4];
#pragma unroll
    for (int jt = 0; jt < 4; ++jt) {
      f32x4 acc = {0.f, 0.f, 0.f, 0.f};
#pragma unroll
      for (int ks = 0; ks < 2; ++ks) {
        int off = (jt * 16 + m16) * AST + ks * 16 + quad * 4;
        bf16x8 kfh = *(const bf16x8*)&Kh[off];
        bf16x8 kfl = *(const bf16x8*)&Kl[off];
        acc = __builtin_amdgcn_mfma_f32_16x16x32_bf16(qfh[ks], kfh, acc, 0, 0, 0);
        acc = __builtin_amdgcn_mfma_f32_16x16x32_bf16(qfh[ks], kfl, acc, 0, 0, 0);
        acc = __builtin_amdgcn_mfma_f32_16x16x32_bf16(qfl[ks], kfh, acc, 0, 0, 0);
      }
      S[jt] = acc;
    }

#pragma unroll
    for (int jt = 0; jt < 4; ++jt) {
      int jc = j0 + jt * 16 + m16;
      if (jc >= JTOT) {
#pragma unroll
        for (int r = 0; r < 4; ++r) S[jt][r] = -INFINITY;
      }
    }

    // ---- online softmax ----
    float pj[4][4];
#pragma unroll
    for (int r = 0; r < 4; ++r) {
      float mx = fmaxf(fmaxf(S[0][r], S[1][r]), fmaxf(S[2][r], S[3][r]));
#pragma unroll
      for (int off = 1; off < 16; off <<= 1)
        mx = fmaxf(mx, __shfl_xor(mx, off, 64));
      float mnew = fmaxf(mrow[r], mx);
      float alpha = __expf(mrow[r] - mnew);
      mrow[r] = mnew;
      float rs = 0.f;
#pragma unroll
      for (int jt = 0; jt < 4; ++jt) {
        float p = __expf(S[jt][r] - mnew);
        pj[jt][r] = p;
        rs += p;
      }
#pragma unroll
      for (int off = 1; off < 16; off <<= 1)
        rs += __shfl_xor(rs, off, 64);
      lrow[r] = lrow[r] * alpha + rs;
#pragma unroll
      for (int nt = 0; nt < 4; ++nt) O[nt][r] *= alpha;
    }

    // ---- write P (interleaved, C-layout) ----
#pragma unroll
    for (int jt = 0; jt < 4; ++jt)
#pragma unroll
      for (int r = 0; r < 4; ++r)
        Pp[(w * 16 + quad * 4 + r) * 68 + jt * 16 + m16] = pack_split(pj[jt][r]);
    __syncthreads();

    // ---- O += P V ----
    bf16x8 ph[2], pl[2];
#pragma unroll
    for (int ks = 0; ks < 2; ++ks) {
      const u32* p = &Pp[(w * 16 + m16) * 68 + ks * 32 + quad * 8];
      uint4 a = *(const uint4*)p, bq = *(const uint4*)(p + 4);
      u32 u[8] = {a.x, a.y, a.z, a.w, bq.x, bq.y, bq.z, bq.w};
      unpack8(u, ph[ks], pl[ks]);
    }
#pragma unroll
    for (int nt = 0; nt < 4; ++nt)
#pragma unroll
      for (int ks = 0; ks < 2; ++ks) {
        int off = (nt * 16 + m16) * AST + ks * 16 + quad * 4;
        bf16x8 vfh = *(const bf16x8*)&Wh[off];
        bf16x8 vfl = *(const bf16x8*)&Wl[off];
        O[nt] = __builtin_amdgcn_mfma_f32_16x16x32_bf16(ph[ks], vfh, O[nt], 0, 0, 0);
        O[nt] = __builtin_amdgcn_mfma_f32_16x16x32_bf16(ph[ks], vfl, O[nt], 0, 0, 0);
        O[nt] = __builtin_amdgcn_mfma_f32_16x16x32_bf16(pl[ks], vfh, O[nt], 0, 0, 0);
      }
  }

  // ---- epilogue: normalize + store ao planes ----
  float inv[4];
#pragma unroll
  for (int r = 0; r < 4; ++r) inv[r] = 1.f / lrow[r];
#pragma unroll
  for (int nt = 0; nt < 4; ++nt)
#pragma unroll
    for (int r = 0; r < 4; ++r) {
      size_t idx = ((size_t)(b * NN + qrow0 + w * 16 + quad * 4 + r)) * INNER +
                   h * 64 + nt * 16 + m16;
      u16 hh, ll;
      split2(O[nt][r] * inv[r], hh, ll);
      aoh[idx] = hh; aol[idx] = ll;
    }
}

// ---------------- launch ----------------
extern "C" void kernel_launch(void* const* d_in, const int* in_sizes, int n_in,
                              void* d_out, int out_size, void* d_ws, size_t ws_size,
                              hipStream_t stream) {
  const float* x        = (const float*)d_in[0];
  const float* context  = (const float*)d_in[1];
  const float* prompt   = (const float*)d_in[2];
  const float* w_prompt = (const float*)d_in[3];
  const float* w_img    = (const float*)d_in[4];
  const float* w_q      = (const float*)d_in[5];
  const float* w_k      = (const float*)d_in[6];
  const float* w_v      = (const float*)d_in[7];
  const float* w_out    = (const float*)d_in[8];
  const float* b_out    = (const float*)d_in[9];
  float* out = (float*)d_out;

  const int M = BB * NN;          // 4096
  const int MJ = BB * JTOT;       // 4378

  u16* p = (u16*)d_ws;
  const size_t qN = (size_t)M * INNER, ctxN = (size_t)MJ * TCD, kvN = (size_t)MJ * INNER;
  u16* qh  = p; p += qN;  u16* ql  = p; p += qN;
  u16* pch = p; p += (size_t)NUM_PROMPT * TCD;
  u16* pcl = p; p += (size_t)NUM_PROMPT * TCD;
  u16* cth = p; p += ctxN; u16* ctl = p; p += ctxN;
  u16* kh  = p; p += kvN;  u16* kl  = p; p += kvN;
  u16* vh  = p; p += kvN;  u16* vl  = p; p += kvN;
  u16* aoh = p; p += qN;   u16* aol = p; p += qN;
  u16* WtPh = p; p += (size_t)TCD * PD;            u16* WtPl = p; p += (size_t)TCD * PD;
  u16* WtAh = p; p += (size_t)(TCD + INNER) * QD;  u16* WtAl = p; p += (size_t)(TCD + INNER) * QD;
  u16* WtBh = p; p += (size_t)(2 * INNER) * TCD;   u16* WtBl = p; p += (size_t)(2 * INNER) * TCD;
  u16* WtOh = p; p += (size_t)QD * INNER;          u16* WtOl = p; p += (size_t)QD * INNER;

  // ---- pack+transpose weights into planes ----
  transpose_pack<<<dim3(TCD / 32, PD / 32), 256, 0, stream>>>(w_prompt, WtPh, WtPl, PD, TCD);
  transpose_pack<<<dim3(TCD / 32, QD / 32), 256, 0, stream>>>(w_img, WtAh, WtAl, QD, TCD);
  transpose_pack<<<dim3(INNER / 32, QD / 32), 256, 0, stream>>>(
      w_q, WtAh + (size_t)TCD * QD, WtAl + (size_t)TCD * QD, QD, INNER);
  transpose_pack<<<dim3(INNER / 32, TCD / 32), 256, 0, stream>>>(w_k, WtBh, WtBl, TCD, INNER);
  transpose_pack<<<dim3(INNER / 32, TCD / 32), 256, 0, stream>>>(
      w_v, WtBh + (size_t)INNER * TCD, WtBl + (size_t)INNER * TCD, TCD, INNER);
  transpose_pack<<<dim3(QD / 32, INNER / 32), 256, 0, stream>>>(w_out, WtOh, WtOl, INNER, QD);

  // ---- prompt_ctx = prompt @ w_prompt -> pc planes ----
  gemm_mfma<0, true><<<dim3(TCD / 128, 1), 256, 0, stream>>>(
      prompt, nullptr, nullptr, WtPh, WtPl, pch, pcl, nullptr, nullptr, nullptr, nullptr,
      NUM_PROMPT, PD, TCD);
  // ---- ctx rows 0..140 ----
  copy_ctx_kernel<<<(BB * 141 * TCD + 255) / 256, 256, 0, stream>>>(context, pch, pcl, cth, ctl);
  // ---- fused: x @ [w_img | w_q] -> ctx planes (remap) + q planes (x SCALE) ----
  gemm_mfma<1, true><<<dim3((TCD + INNER) / 128, M / 128), 256, 0, stream>>>(
      x, nullptr, nullptr, WtAh, WtAl, cth, ctl, qh, ql, nullptr, nullptr,
      M, QD, TCD + INNER);
  // ---- fused: ctx @ [w_k | w_v] -> k/v planes ----
  gemm_mfma<2, false><<<dim3((2 * INNER) / 128, (MJ + 127) / 128), 256, 0, stream>>>(
      nullptr, cth, ctl, WtBh, WtBl, kh, kl, vh, vl, nullptr, nullptr,
      MJ, TCD, 2 * INNER);
  // ---- attention ----
  attn_mfma<<<BB * HEADS * (NN / 64), 256, 0, stream>>>(qh, ql, kh, kl, vh, vl, aoh, aol);
  // ---- out = ao @ w_out + b_out (f32) ----
  gemm_mfma<3, false><<<dim3(QD / 128, M / 128), 256, 0, stream>>>(
      nullptr, aoh, aol, WtOh, WtOl, nullptr, nullptr, nullptr, nullptr, out, b_out,
      M, INNER, QD);
}